// Round 14
// baseline (388.628 us; speedup 1.0000x reference)
//
#include <hip/hip_runtime.h>
#include <hip/hip_bf16.h>

#define NN 50000          // nodes
#define NE 800000         // edges
#define NR 3              // relations
#define NG 500            // graphs
#define NB (NN * NR)      // (dst, rel) buckets = 150000
#define NCLS 10
#define NCMB 8192         // 8 shapes * 8 colors * 128 positions
#define CHUNK 2048        // scan elements per block
#define NBLK ((NB + CHUNK - 1) / CHUNK)   // 74

// prep1 role block ranges
#define P1_COMBO   196                        // node_combo: 50000/256
#define P1_ZCNT    586                        // zero cnt: 150000/256
#define P1_ZPOOL   502                        // zero pool+gcnt: 128500/256
#define P1_TAB     576                        // tab_gemm: 4*144
#define P1_WF      1024                       // conv_w2cat: 256*1024/256
#define P1_TOTAL   (P1_COMBO + P1_ZCNT + P1_ZPOOL + P1_TAB + P1_WF)   // 2884
// prep2 role block ranges
#define P2_CNT     3125                       // count_edges: NE/256
#define P2_TB      768                        // tb2 build: 256 SC rows + 512 P rows
#define P2_TOTAL   (P2_CNT + P2_TB)           // 3893

// l1_hist geometry
#define L1_DPB     64                         // dsts per block
#define L1_HS      776                        // hist row stride (bytes; breaks 768 bank pattern)
#define L1_BLOCKS  ((NN + L1_DPB - 1) / L1_DPB)   // 782

typedef __hip_bfloat16 bf16;
typedef __attribute__((ext_vector_type(8))) short short8;   // bf16x8 MFMA frag
typedef __attribute__((ext_vector_type(4))) short shortx4;  // bf16x4 gather unit
typedef __attribute__((ext_vector_type(4))) float floatx4;  // MFMA accumulator

static __device__ __forceinline__ float b2f(bf16 x) { return __bfloat162float(x); }
static __device__ __forceinline__ bf16  f2b(float x) { return __float2bfloat16(x); }
static __device__ __forceinline__ float bs2f(short x) {
    return __bfloat162float(*reinterpret_cast<const bf16*>(&x));
}
static __device__ __forceinline__ short f2bs(float x) {
    bf16 b = __float2bfloat16(x);
    return *reinterpret_cast<const short*>(&b);
}
static __device__ __forceinline__ int rfl(int x) {
    return __builtin_amdgcn_readfirstlane(x);
}

// ---------------- prep1: all independent prep work, role-dispatched by blockIdx
__global__ __launch_bounds__(256) void prep1(const int* __restrict__ s,
                                             const int* __restrict__ c,
                                             const int* __restrict__ p,
                                             const float* __restrict__ se,
                                             const float* __restrict__ ce,
                                             const float* __restrict__ pe,
                                             const float* __restrict__ W1,
                                             const float* __restrict__ root1,
                                             const float* __restrict__ W2,
                                             const float* __restrict__ root2,
                                             int* __restrict__ combo,
                                             unsigned* __restrict__ cnt,
                                             unsigned* __restrict__ poolz,
                                             float* __restrict__ tab,
                                             bf16* __restrict__ Wf) {
    int b = blockIdx.x, t = threadIdx.x;
    if (b < P1_COMBO) {
        int n = b * 256 + t;
        if (n < NN) combo[n] = (s[n] << 10) | (c[n] << 7) | p[n];
        return;
    }
    b -= P1_COMBO;
    if (b < P1_ZCNT) {
        int i = b * 256 + t;
        if (i < NB) cnt[i] = 0u;
        return;
    }
    b -= P1_ZCNT;
    if (b < P1_ZPOOL) {
        int i = b * 256 + t;
        if (i < NG * 256 + NG) poolz[i] = 0u;
        return;
    }
    b -= P1_ZPOOL;
    if (b < P1_TAB) {
        // tab[r][row][n]: rows 0..7 = se@Wseg0, 8..15 = ce@Wseg1, 16..143 = pe@Wseg2
        int r = b / 144, row = b % 144;
        const float* A; int segk;
        if (row < 8)       { A = se + row * 128;        segk = 0; }
        else if (row < 16) { A = ce + (row - 8) * 128;  segk = 128; }
        else               { A = pe + (row - 16) * 128; segk = 256; }
        const float* W = (r < 3) ? (W1 + (size_t)r * 384 * 256) : root1;
        float acc = 0.f;
        for (int k = 0; k < 128; ++k)
            acc += A[k] * W[(size_t)(segk + k) * 256 + t];
        tab[((size_t)r * 144 + row) * 256 + t] = acc;
        return;
    }
    b -= P1_TAB;
    {   // conv_w2cat: Wf in MFMA-fragment order (wave B-frag = contiguous 1 KB)
        int idx = b * 256 + t;
        int j     = idx & 7;
        int lane  = (idx >> 3) & 63;
        int ni    = (idx >> 9) & 3;
        int chunk = (idx >> 11) & 31;
        int colblk = idx >> 16;
        int col = colblk * 64 + ni * 16 + (lane & 15);
        int k   = chunk * 32 + (lane >> 4) * 8 + j;
        float v = (k < 768) ? W2[((size_t)(k >> 8) * 256 + (k & 255)) * 256 + col]
                            : root2[(size_t)(k - 768) * 256 + col];
        Wf[idx] = f2b(v);
    }
}

// ---------------- prep2: count_edges + L2-resident table build
// tb2 rows [0,256): tabSC[r][s*8+c] = tab[r][s]+tab[r][8+c] (+b1 for r=3)
// tb2 rows [256,768): tabP[r][p]    = tab[r][16+p]
__global__ __launch_bounds__(256) void prep2(const int* __restrict__ ei,
                                             const int* __restrict__ et,
                                             int* __restrict__ cnt,
                                             const float* __restrict__ tab,
                                             const float* __restrict__ b1,
                                             bf16* __restrict__ tb2) {
    int b = blockIdx.x, t = threadIdx.x;
    if (b < P2_CNT) {
        int e = b * 256 + t;
        if (e < NE) atomicAdd(&cnt[ei[NE + e] * NR + et[e]], 1);
        return;
    }
    b -= P2_CNT;
    if (b < 256) {          // SC rows
        int r = b >> 6, sc = b & 63, si = sc >> 3, ci = sc & 7;
        float v = tab[((size_t)r * 144 + si) * 256 + t]
                + tab[((size_t)r * 144 + 8 + ci) * 256 + t];
        if (r == 3) v += b1[t];
        tb2[(size_t)b * 256 + t] = f2b(v);
    } else {                // P rows
        int bb = b - 256;
        int r = bb >> 7, pi = bb & 127;
        tb2[(size_t)(256 + bb) * 256 + t] =
            f2b(tab[((size_t)r * 144 + 16 + pi) * 256 + t]);
    }
}

// ---------------- prep3: tbf = fragment-ordered copy of tb2 (768 K x 256 cols)
__global__ __launch_bounds__(256) void prep3(const bf16* __restrict__ tb2,
                                             bf16* __restrict__ tbf) {
    int idx = blockIdx.x * 256 + threadIdx.x;       // < 768*256 = 196608
    int j = idx & 7, lane = (idx >> 3) & 63, ni = (idx >> 9) & 3;
    int rest = idx >> 11;                           // colblk*24 + chunk, < 96
    int chunk = rest % 24, colblk = rest / 24;
    int col = colblk * 64 + ni * 16 + (lane & 15);
    int k   = chunk * 32 + (lane >> 4) * 8 + j;
    tbf[idx] = tb2[(size_t)k * 256 + col];
}

// ---------------- counting-sort scan, phase A: per-block (2048-elem) totals
__global__ __launch_bounds__(256) void scan_block_sums(const int* __restrict__ cnt,
                                                       int* __restrict__ bsum) {
    __shared__ int sm[256];
    int b = blockIdx.x, t = threadIdx.x;
    int base = b * CHUNK + t * 8, s = 0;
#pragma unroll
    for (int j = 0; j < 8; ++j) { int i = base + j; if (i < NB) s += cnt[i]; }
    sm[t] = s; __syncthreads();
    for (int st = 128; st; st >>= 1) { if (t < st) sm[t] += sm[t + st]; __syncthreads(); }
    if (!t) bsum[b] = sm[0];
}

// ---------------- phase B+C merged: 74-elem wave-uniform prefix over bsum + in-block scan
__global__ __launch_bounds__(256) void scan_write(const int* __restrict__ cnt,
                                                  const int* __restrict__ bsum,
                                                  int* __restrict__ off,
                                                  int* __restrict__ cursor) {
    int b = blockIdx.x, t = threadIdx.x;
    int bbase = 0;                              // wave-uniform 74-iteration prefix
    for (int i = 0; i < b; ++i) bbase += bsum[i];
    if (b == 0 && t == 0) {
        int tot = 0;
        for (int i = 0; i < NBLK; ++i) tot += bsum[i];
        off[NB] = tot;                          // == NE
    }
    int base = b * CHUNK + t * 8;
    int v[8], ts = 0;
#pragma unroll
    for (int j = 0; j < 8; ++j) { int i = base + j; v[j] = (i < NB) ? cnt[i] : 0; ts += v[j]; }
    int lane = t & 63, wv = t >> 6;
    int incl = ts;
    for (int d = 1; d < 64; d <<= 1) {
        int o = __shfl_up(incl, d, 64);
        if (lane >= d) incl += o;
    }
    __shared__ int wsum[4];
    if (lane == 63) wsum[wv] = incl;
    __syncthreads();
    int wbase = 0;
    for (int w = 0; w < wv; ++w) wbase += wsum[w];
    int run = bbase + wbase + incl - ts;
#pragma unroll
    for (int j = 0; j < 8; ++j) {
        int i = base + j;
        if (i < NB) { off[i] = run; cursor[i] = run; }
        run += v[j];
    }
}

// ---------------- bucket-sort edges: single packed-4B scatter
// esc entry = (src << 13) | combo[src]   (src < 2^16, combo < 2^13)
__global__ __launch_bounds__(256) void scatter_edges(const int* __restrict__ ei,
                                                     const int* __restrict__ et,
                                                     const int* __restrict__ combo,
                                                     int* __restrict__ cursor,
                                                     unsigned* __restrict__ esc) {
    int e = blockIdx.x * 256 + threadIdx.x;
    if (e >= NE) return;
    int b = ei[NE + e] * NR + et[e];
    int pos = atomicAdd(&cursor[b], 1);
    int s = ei[e];
    esc[pos] = ((unsigned)s << 13) | (unsigned)combo[s];
}

// ---------------- layer 1 as histogram-GEMM (validated r11: VALU gather -> MFMA)
__global__ __launch_bounds__(256) void l1_hist(const int* __restrict__ off,
                                               const unsigned* __restrict__ esc,
                                               const int* __restrict__ combo,
                                               const bf16* __restrict__ tbf,
                                               bf16* __restrict__ h1) {
    __shared__ __align__(16) unsigned char HIST[L1_DPB * L1_HS];   // 49664 B
    __shared__ int SOFF[193];
    __shared__ float INV[L1_DPB][4];
    const int t = threadIdx.x;
    const int dst0 = blockIdx.x * L1_DPB;

    // ---- phase 1: zero hist + load (clamped) bucket offsets
    for (int i = t; i < (L1_DPB * L1_HS) / 4; i += 256)
        ((unsigned*)HIST)[i] = 0u;
    for (int i = t; i < 193; i += 256)
        SOFF[i] = off[min(dst0 * NR + i, NB)];
    __syncthreads();

    // ---- phase 2: inv table, root one-hots, edge histogram
    if (t < L1_DPB) {
        int base = 3 * t;
#pragma unroll
        for (int r = 0; r < 3; ++r) {
            int c = SOFF[base + r + 1] - SOFF[base + r];
            INV[t][r] = (c > 0) ? 1.f / (float)c : 0.f;
        }
        INV[t][3] = 1.f;
        if (dst0 + t < NN) {                    // root one-hots (rel-3 rows: no
            int c = combo[dst0 + t];            //  overlap with edge rows)
            HIST[t * L1_HS + 192 + (c >> 7)] = 1;
            HIST[t * L1_HS + 640 + (c & 127)] = 1;
        }
    }
    int E0 = SOFF[0], E1 = SOFF[192];
    for (int e = E0 + t; e < E1; e += 256) {    // coalesced esc stream
        unsigned ev = esc[e];
        int lo = 0, hi = 191;                   // largest i with SOFF[i] <= e
#pragma unroll 1
        while (lo < hi) {
            int mid = (lo + hi + 1) >> 1;
            if (SOFF[mid] <= e) lo = mid; else hi = mid - 1;
        }
        int dr = lo / 3, rel = lo - dr * 3;
        int sc = (int)((ev & 8191u) >> 7), p = (int)(ev & 127u);
        int a1 = dr * L1_HS + rel * 64 + sc;            // SC row
        int a2 = dr * L1_HS + 256 + rel * 128 + p;      // P row
        atomicAdd((unsigned*)&HIST[a1 & ~3], 1u << (8 * (a1 & 3)));
        atomicAdd((unsigned*)&HIST[a2 & ~3], 1u << (8 * (a2 & 3)));
    }
    __syncthreads();

    // ---- phase 3: GEMM 64x768 @ 768x256, A from LDS hist, B frags from tbf
    const int wave = t >> 6, lane = t & 63;
    const int quad = lane >> 4, l16 = lane & 15;
    const short8* bb = (const short8*)tbf + (size_t)wave * 24 * 4 * 64 + lane;
    floatx4 acc[4][4] = {};
#pragma unroll 4
    for (int ch = 0; ch < 24; ++ch) {
        short8 bf_[4];
        const short8* bp = bb + (size_t)ch * 4 * 64;
#pragma unroll
        for (int ni = 0; ni < 4; ++ni) bf_[ni] = bp[ni * 64];
        int kb = ch * 32 + quad * 8;
        int iv = (kb < 256) ? (kb >> 6) : ((kb - 256) >> 7);
#pragma unroll
        for (int mi = 0; mi < 4; ++mi) {
            int row = mi * 16 + l16;
            unsigned hx = *(const unsigned*)&HIST[row * L1_HS + kb];
            unsigned hy = *(const unsigned*)&HIST[row * L1_HS + kb + 4];
            float w = INV[row][iv];
            short8 af;
            af[0] = f2bs((float)(hx & 0xffu) * w);
            af[1] = f2bs((float)((hx >> 8) & 0xffu) * w);
            af[2] = f2bs((float)((hx >> 16) & 0xffu) * w);
            af[3] = f2bs((float)(hx >> 24) * w);
            af[4] = f2bs((float)(hy & 0xffu) * w);
            af[5] = f2bs((float)((hy >> 8) & 0xffu) * w);
            af[6] = f2bs((float)((hy >> 16) & 0xffu) * w);
            af[7] = f2bs((float)(hy >> 24) * w);
#pragma unroll
            for (int ni = 0; ni < 4; ++ni)
                acc[mi][ni] = __builtin_amdgcn_mfma_f32_16x16x32_bf16(af, bf_[ni], acc[mi][ni], 0, 0, 0);
        }
    }

    // ---- phase 4: relu + stage (reuse hist LDS, stride 264 shorts) + write
    __syncthreads();
    short* st = (short*)HIST;                   // 64*264*2 = 33792 B <= 49664
    // C/D layout: col = lane&15, row = quad*4 + reg   [m89/m91-verified]
#pragma unroll
    for (int mi = 0; mi < 4; ++mi)
#pragma unroll
        for (int ni = 0; ni < 4; ++ni)
#pragma unroll
            for (int ii = 0; ii < 4; ++ii) {
                int row = mi * 16 + quad * 4 + ii;
                int col = wave * 64 + ni * 16 + l16;
                st[row * 264 + col] = f2bs(fmaxf(acc[mi][ni][ii], 0.f));
            }
    __syncthreads();
    int row = t >> 2, cb = (t & 3) * 64;
    if (dst0 + row < NN) {
#pragma unroll
        for (int j = 0; j < 8; ++j)
            *(short8*)(h1 + (size_t)(dst0 + row) * 256 + cb + j * 8) =
                *(const short8*)&st[row * 264 + cb + j * 8];
    }
}

// ---------------- per-relation mean aggregation v4 (validated r12): maskless
// common prefix + short masked tails; 6 exact rows in flight; scalar CSR/esc.
__global__ __launch_bounds__(256, 4) void agg_all(const int* __restrict__ off,
                                                  const unsigned* __restrict__ esc,
                                                  const bf16* __restrict__ h1,
                                                  bf16* __restrict__ hagg) {
    int wave = threadIdx.x >> 6, lane = threadIdx.x & 63;
    int dst = blockIdx.x * 4 + wave;
    if (dst >= NN) return;
    int l4 = lane * 4;
    int b0 = dst * NR;
    int o0 = rfl(off[b0]),     o1 = rfl(off[b0 + 1]),
        o2 = rfl(off[b0 + 2]), o3 = rfl(off[b0 + 3]);
    int nmin = min(o1 - o0, min(o2 - o1, o3 - o2));
    float s0[4] = {}, s1[4] = {}, s2[4] = {};
    int k = 0;
    for (; k + 2 <= nmin; k += 2) {             // 6 exact rows in flight, maskless
        unsigned ea0 = esc[o0 + k], ea1 = esc[o0 + k + 1];
        unsigned eb0 = esc[o1 + k], eb1 = esc[o1 + k + 1];
        unsigned ec0 = esc[o2 + k], ec1 = esc[o2 + k + 1];
        shortx4 va0 = *(const shortx4*)(h1 + (size_t)(ea0 >> 13) * 256 + l4);
        shortx4 va1 = *(const shortx4*)(h1 + (size_t)(ea1 >> 13) * 256 + l4);
        shortx4 vb0 = *(const shortx4*)(h1 + (size_t)(eb0 >> 13) * 256 + l4);
        shortx4 vb1 = *(const shortx4*)(h1 + (size_t)(eb1 >> 13) * 256 + l4);
        shortx4 vc0 = *(const shortx4*)(h1 + (size_t)(ec0 >> 13) * 256 + l4);
        shortx4 vc1 = *(const shortx4*)(h1 + (size_t)(ec1 >> 13) * 256 + l4);
#pragma unroll
        for (int i = 0; i < 4; ++i) {
            s0[i] += bs2f(va0[i]) + bs2f(va1[i]);
            s1[i] += bs2f(vb0[i]) + bs2f(vb1[i]);
            s2[i] += bs2f(vc0[i]) + bs2f(vc1[i]);
        }
    }
    // per-relation tails, 2-deep, <=1 duplicate load when tail length odd
    for (int j = o0 + k; j < o1; j += 2) {
        bool g = j + 1 < o1;
        unsigned e0 = esc[j], e1 = esc[g ? j + 1 : j];
        shortx4 v0 = *(const shortx4*)(h1 + (size_t)(e0 >> 13) * 256 + l4);
        shortx4 v1 = *(const shortx4*)(h1 + (size_t)(e1 >> 13) * 256 + l4);
        float m = g ? 1.f : 0.f;
#pragma unroll
        for (int i = 0; i < 4; ++i) s0[i] += bs2f(v0[i]) + bs2f(v1[i]) * m;
    }
    for (int j = o1 + k; j < o2; j += 2) {
        bool g = j + 1 < o2;
        unsigned e0 = esc[j], e1 = esc[g ? j + 1 : j];
        shortx4 v0 = *(const shortx4*)(h1 + (size_t)(e0 >> 13) * 256 + l4);
        shortx4 v1 = *(const shortx4*)(h1 + (size_t)(e1 >> 13) * 256 + l4);
        float m = g ? 1.f : 0.f;
#pragma unroll
        for (int i = 0; i < 4; ++i) s1[i] += bs2f(v0[i]) + bs2f(v1[i]) * m;
    }
    for (int j = o2 + k; j < o3; j += 2) {
        bool g = j + 1 < o3;
        unsigned e0 = esc[j], e1 = esc[g ? j + 1 : j];
        shortx4 v0 = *(const shortx4*)(h1 + (size_t)(e0 >> 13) * 256 + l4);
        shortx4 v1 = *(const shortx4*)(h1 + (size_t)(e1 >> 13) * 256 + l4);
        float m = g ? 1.f : 0.f;
#pragma unroll
        for (int i = 0; i < 4; ++i) s2[i] += bs2f(v0[i]) + bs2f(v1[i]) * m;
    }
    float inv0 = (o1 > o0) ? 1.f / (float)(o1 - o0) : 0.f;
    float inv1 = (o2 > o1) ? 1.f / (float)(o2 - o1) : 0.f;
    float inv2 = (o3 > o2) ? 1.f / (float)(o3 - o2) : 0.f;
    shortx4 w0, w1, w2;
#pragma unroll
    for (int i = 0; i < 4; ++i) {
        w0[i] = f2bs(s0[i] * inv0);
        w1[i] = f2bs(s1[i] * inv1);
        w2[i] = f2bs(s2[i] * inv2);
    }
    bf16* hd = hagg + (size_t)dst * 768 + l4;
    *(shortx4*)(hd)       = w0;
    *(shortx4*)(hd + 256) = w1;
    *(shortx4*)(hd + 512) = w2;
}

// ---------------- concat MFMA GEMM v10: 32 rows/block, NO LDS in the K-loop.
// A-fragments loaded DIRECTLY from global in MFMA layout (lane reads row
// lane&15 at k-offset (lane>>4)*8; lanes {l,l+16,l+32,l+48} cover one 64 B
// run per row -> identical coalescing to the staged form). Removes the
// ds_write->lgkmcnt->ds_read chain and its 4.8 M bank-conflict cycles.
// LDS only for the epilogue tile. + fused bias/relu + fused RLE pooling.
__global__ __launch_bounds__(256) void gemm_cat(const bf16* __restrict__ hagg,
                                                const bf16* __restrict__ h1,
                                                const bf16* __restrict__ Wf,
                                                const float* __restrict__ bias,
                                                const int* __restrict__ batch,
                                                float* __restrict__ pool,
                                                float* __restrict__ gcnt) {
    __shared__ short st[32 * 264];          // epilogue staging only (16896 B)
    const int t = threadIdx.x;
    const int wave = t >> 6, lane = t & 63;
    const int quad = lane >> 4, l16 = lane & 15;
    const int row0 = blockIdx.x * 32;
    const int colblk = wave;                // 0..3 -> 64-col group

    // direct fragment addressing: this lane's A rows and k-slice
    const int r0 = min(row0 + l16, NN - 1);         // clamped (uses guarded)
    const int r1 = min(row0 + 16 + l16, NN - 1);
    const bf16* gA0 = hagg + (size_t)r0 * 768 + quad * 8;
    const bf16* gA1 = hagg + (size_t)r1 * 768 + quad * 8;
    const bf16* gH0 = h1 + (size_t)r0 * 256 + quad * 8;
    const bf16* gH1 = h1 + (size_t)r1 * 256 + quad * 8;
    const short8* bbase = (const short8*)Wf + (size_t)colblk * 32 * 4 * 64 + lane;

    auto loadA2 = [&](int k0, short8& a0, short8& a1) {
        if (k0 < 768) { a0 = *(const short8*)(gA0 + k0); a1 = *(const short8*)(gA1 + k0); }
        else          { a0 = *(const short8*)(gH0 + k0 - 768); a1 = *(const short8*)(gH1 + k0 - 768); }
    };
    auto loadB = [&](int chunk, short8* bf4) {
        const short8* bp = bbase + (size_t)chunk * 4 * 64;
#pragma unroll
        for (int ni = 0; ni < 4; ++ni) bf4[ni] = bp[ni * 64];
    };

    floatx4 acc[2][4] = {};
    short8 aE0, aE1, bE[4];     // even-chunk register set (fragments, ready to feed MFMA)
    short8 aO0, aO1, bO[4];     // odd-chunk register set
    loadA2(0, aE0, aE1);  loadB(0, bE);
    loadA2(32, aO0, aO1); loadB(1, bO);

#pragma unroll
    for (int i = 0; i < 32; i += 2) {
        // ---- even chunk i: set E straight into MFMA
#pragma unroll
        for (int ni = 0; ni < 4; ++ni) {
            acc[0][ni] = __builtin_amdgcn_mfma_f32_16x16x32_bf16(aE0, bE[ni], acc[0][ni], 0, 0, 0);
            acc[1][ni] = __builtin_amdgcn_mfma_f32_16x16x32_bf16(aE1, bE[ni], acc[1][ni], 0, 0, 0);
        }
        if (i + 2 < 32) { loadA2((i + 2) * 32, aE0, aE1); loadB(i + 2, bE); }
        // ---- odd chunk i+1: set O
#pragma unroll
        for (int ni = 0; ni < 4; ++ni) {
            acc[0][ni] = __builtin_amdgcn_mfma_f32_16x16x32_bf16(aO0, bO[ni], acc[0][ni], 0, 0, 0);
            acc[1][ni] = __builtin_amdgcn_mfma_f32_16x16x32_bf16(aO1, bO[ni], acc[1][ni], 0, 0, 0);
        }
        if (i + 3 < 32) { loadA2((i + 3) * 32, aO0, aO1); loadB(i + 3, bO); }
    }

    // ---- epilogue: stage bf16 h2 tile into LDS (stride 264), then RLE pooling
    // C/D layout: col = lane&15, row = quad*4 + reg   [m89/m91-verified]
#pragma unroll
    for (int mi = 0; mi < 2; ++mi) {
#pragma unroll
        for (int ni = 0; ni < 4; ++ni) {
            int n = colblk * 64 + ni * 16 + l16;
            float bn = bias[n];
#pragma unroll
            for (int ii = 0; ii < 4; ++ii) {
                int lrow = mi * 16 + quad * 4 + ii;
                float v = (row0 + lrow < NN) ? fmaxf(acc[mi][ni][ii] + bn, 0.f) : 0.f;
                st[lrow * 264 + n] = f2bs(v);
            }
        }
    }
    __syncthreads();
    int nrows = NN - row0; if (nrows > 32) nrows = 32;
    int curg = batch[row0];                 // wave-uniform broadcast
    float a = 0.f, cntf = 0.f;
    for (int rr = 0; rr < nrows; ++rr) {
        int g = batch[row0 + rr];
        if (g != curg) {
            atomicAdd(&pool[(size_t)curg * 256 + t], a);
            if (t == 0) atomicAdd(&gcnt[curg], cntf);
            a = 0.f; cntf = 0.f; curg = g;
        }
        a += bs2f(st[rr * 264 + t]);
        cntf += 1.f;
    }
    atomicAdd(&pool[(size_t)curg * 256 + t], a);
    if (t == 0) atomicAdd(&gcnt[curg], cntf);
}

// ---------------- head: out[g][c] = (pool[g]/cnt[g]) @ lin_w + lin_b  (f32 out)
__global__ __launch_bounds__(256) void final_head(const float* __restrict__ pool,
                                                  const float* __restrict__ gcnt,
                                                  const float* __restrict__ lin_w,
                                                  const float* __restrict__ lin_b,
                                                  float* __restrict__ out) {
    __shared__ float sm[256];
    int g = blockIdx.x, t = threadIdx.x;
    float inv = 1.0f / fmaxf(gcnt[g], 1.0f);
    sm[t] = pool[(size_t)g * 256 + t] * inv;
    __syncthreads();
    if (t < NCLS) {
        float s = lin_b[t];
        for (int d = 0; d < 256; ++d) s += sm[d] * lin_w[d * NCLS + t];
        out[g * NCLS + t] = s;
    }
}

extern "C" void kernel_launch(void* const* d_in, const int* in_sizes, int n_in,
                              void* d_out, int out_size, void* d_ws, size_t ws_size,
                              hipStream_t stream) {
    const int*   s_idx = (const int*)d_in[0];
    const int*   c_idx = (const int*)d_in[1];
    const int*   p_idx = (const int*)d_in[2];
    const int*   ei    = (const int*)d_in[3];   // (2, NE)
    const int*   et    = (const int*)d_in[4];
    const int*   batch = (const int*)d_in[5];
    const float* se    = (const float*)d_in[6];
    const float* ce    = (const float*)d_in[7];
    const float* pe    = (const float*)d_in[8];
    const float* W1    = (const float*)d_in[9];   // (3, 384, 256)
    const float* root1 = (const float*)d_in[10];  // (384, 256)
    const float* b1    = (const float*)d_in[11];
    const float* W2    = (const float*)d_in[12];  // (3, 256, 256)
    const float* root2 = (const float*)d_in[13];  // (256, 256)
    const float* b2    = (const float*)d_in[14];
    const float* lin_w = (const float*)d_in[15];
    const float* lin_b = (const float*)d_in[16];
    float* out = (float*)d_out;

    // ---- workspace carve-up (~129 MB)
    char* w = (char*)d_ws;
    size_t o = 0;
    auto alloc = [&](size_t bytes) -> void* {
        o = (o + 15) & ~(size_t)15;
        void* ptr = w + o;
        o += bytes;
        return ptr;
    };
    bf16*     hagg   = (bf16*)    alloc((size_t)NN * 768 * 2);   // 76.8 MB
    bf16*     h1     = (bf16*)    alloc((size_t)NN * 256 * 2);
    bf16*     tb2    = (bf16*)    alloc((size_t)768 * 256 * 2);  // 393 KB L2-resident tables
    bf16*     tbf    = (bf16*)    alloc((size_t)768 * 256 * 2);  // fragment-ordered tb2
    int*      combo  = (int*)     alloc((size_t)NN * 4);
    unsigned* esc    = (unsigned*)alloc((size_t)NE * 4);   // (src<<13)|combo
    int*      cnt    = (int*)     alloc((size_t)NB * 4);
    int*      off    = (int*)     alloc((size_t)(NB + 1) * 4);
    int*      cursor = (int*)     alloc((size_t)NB * 4);
    int*      bsum   = (int*)     alloc((size_t)NBLK * 4);
    float*    tab    = (float*)   alloc((size_t)4 * 144 * 256 * 4);
    bf16*     Wf     = (bf16*)    alloc((size_t)256 * 1024 * 2);
    float*    pool   = (float*)   alloc((size_t)NG * 256 * 4);  // pool + gcnt contiguous
    float*    gcnt   = (float*)   alloc((size_t)NG * 4);
    (void)ws_size;

    // ---- 1. all independent prep (combo ids, zeros, layer-1 tab GEMM, Wf shuffle)
    prep1<<<P1_TOTAL, 256, 0, stream>>>(s_idx, c_idx, p_idx, se, ce, pe,
                                        W1, root1, W2, root2,
                                        combo, (unsigned*)cnt, (unsigned*)pool, tab, Wf);
    // ---- 2. edge counts + SC/P table build
    prep2<<<P2_TOTAL, 256, 0, stream>>>(ei, et, cnt, tab, b1, tb2);
    // ---- 2b. fragment-ordered tb2 for the l1 GEMM
    prep3<<<768, 256, 0, stream>>>(tb2, tbf);
    // ---- 3-4. CSR scan (two-kernel form: parallel block sums + cheap bsum prefix)
    scan_block_sums<<<NBLK, 256, 0, stream>>>(cnt, bsum);
    scan_write<<<NBLK, 256, 0, stream>>>(cnt, bsum, off, cursor);
    // ---- 5. bucket-sort edges (packed 4B scatter)
    scatter_edges<<<(NE + 255) / 256, 256, 0, stream>>>(ei, et, combo, cursor, esc);
    // ---- 6. layer 1 as histogram-GEMM (VALU gather -> MFMA)
    l1_hist<<<L1_BLOCKS, 256, 0, stream>>>(off, esc, combo, tbf, h1);
    // ---- 7. layer 2 aggregation (v4: maskless prefix + short tails)
    agg_all<<<(NN + 3) / 4, 256, 0, stream>>>(off, esc, h1, hagg);
    // ---- 8. concat GEMM v10 (direct-reg A frags, no K-loop LDS) + bias/relu + pooling
    gemm_cat<<<(NN + 31) / 32, 256, 0, stream>>>(hagg, h1, Wf, b2, batch, pool, gcnt);
    // ---- 9. head
    final_head<<<NG, 256, 0, stream>>>(pool, gcnt, lin_w, lin_b, out);
}

// Round 15
// 360.658 us; speedup vs baseline: 1.0776x; 1.0776x over previous
//
#include <hip/hip_runtime.h>
#include <hip/hip_bf16.h>

#define NN 50000          // nodes
#define NE 800000         // edges
#define NR 3              // relations
#define NG 500            // graphs
#define NB (NN * NR)      // (dst, rel) buckets = 150000
#define NCLS 10
#define NCMB 8192         // 8 shapes * 8 colors * 128 positions
#define CHUNK 2048        // scan elements per block
#define NBLK ((NB + CHUNK - 1) / CHUNK)   // 74

// prep1 role block ranges
#define P1_COMBO   196                        // node_combo: 50000/256
#define P1_ZCNT    586                        // zero cnt: 150000/256
#define P1_ZPOOL   502                        // zero pool+gcnt: 128500/256
#define P1_TAB     576                        // tab_gemm: 4*144
#define P1_WF      1024                       // conv_w2cat: 256*1024/256
#define P1_TOTAL   (P1_COMBO + P1_ZCNT + P1_ZPOOL + P1_TAB + P1_WF)   // 2884
// prep2 role block ranges
#define P2_CNT     3125                       // count_edges: NE/256
#define P2_TB      768                        // tb2 build: 256 SC rows + 512 P rows
#define P2_TOTAL   (P2_CNT + P2_TB)           // 3893

// l1_hist geometry
#define L1_DPB     64                         // dsts per block
#define L1_HS      776                        // hist row stride (bytes; breaks 768 bank pattern)
#define L1_BLOCKS  ((NN + L1_DPB - 1) / L1_DPB)   // 782

typedef __hip_bfloat16 bf16;
typedef __attribute__((ext_vector_type(8))) short short8;   // bf16x8 MFMA frag
typedef __attribute__((ext_vector_type(4))) short shortx4;  // bf16x4 gather unit
typedef __attribute__((ext_vector_type(4))) float floatx4;  // MFMA accumulator

static __device__ __forceinline__ float b2f(bf16 x) { return __bfloat162float(x); }
static __device__ __forceinline__ bf16  f2b(float x) { return __float2bfloat16(x); }
static __device__ __forceinline__ float bs2f(short x) {
    return __bfloat162float(*reinterpret_cast<const bf16*>(&x));
}
static __device__ __forceinline__ short f2bs(float x) {
    bf16 b = __float2bfloat16(x);
    return *reinterpret_cast<const short*>(&b);
}
static __device__ __forceinline__ int rfl(int x) {
    return __builtin_amdgcn_readfirstlane(x);
}

// ---------------- prep1: all independent prep work, role-dispatched by blockIdx
__global__ __launch_bounds__(256) void prep1(const int* __restrict__ s,
                                             const int* __restrict__ c,
                                             const int* __restrict__ p,
                                             const float* __restrict__ se,
                                             const float* __restrict__ ce,
                                             const float* __restrict__ pe,
                                             const float* __restrict__ W1,
                                             const float* __restrict__ root1,
                                             const float* __restrict__ W2,
                                             const float* __restrict__ root2,
                                             int* __restrict__ combo,
                                             unsigned* __restrict__ cnt,
                                             unsigned* __restrict__ poolz,
                                             float* __restrict__ tab,
                                             bf16* __restrict__ Wf) {
    int b = blockIdx.x, t = threadIdx.x;
    if (b < P1_COMBO) {
        int n = b * 256 + t;
        if (n < NN) combo[n] = (s[n] << 10) | (c[n] << 7) | p[n];
        return;
    }
    b -= P1_COMBO;
    if (b < P1_ZCNT) {
        int i = b * 256 + t;
        if (i < NB) cnt[i] = 0u;
        return;
    }
    b -= P1_ZCNT;
    if (b < P1_ZPOOL) {
        int i = b * 256 + t;
        if (i < NG * 256 + NG) poolz[i] = 0u;
        return;
    }
    b -= P1_ZPOOL;
    if (b < P1_TAB) {
        // tab[r][row][n]: rows 0..7 = se@Wseg0, 8..15 = ce@Wseg1, 16..143 = pe@Wseg2
        int r = b / 144, row = b % 144;
        const float* A; int segk;
        if (row < 8)       { A = se + row * 128;        segk = 0; }
        else if (row < 16) { A = ce + (row - 8) * 128;  segk = 128; }
        else               { A = pe + (row - 16) * 128; segk = 256; }
        const float* W = (r < 3) ? (W1 + (size_t)r * 384 * 256) : root1;
        float acc = 0.f;
        for (int k = 0; k < 128; ++k)
            acc += A[k] * W[(size_t)(segk + k) * 256 + t];
        tab[((size_t)r * 144 + row) * 256 + t] = acc;
        return;
    }
    b -= P1_TAB;
    {   // conv_w2cat: Wf in MFMA-fragment order (wave B-frag = contiguous 1 KB)
        int idx = b * 256 + t;
        int j     = idx & 7;
        int lane  = (idx >> 3) & 63;
        int ni    = (idx >> 9) & 3;
        int chunk = (idx >> 11) & 31;
        int colblk = idx >> 16;
        int col = colblk * 64 + ni * 16 + (lane & 15);
        int k   = chunk * 32 + (lane >> 4) * 8 + j;
        float v = (k < 768) ? W2[((size_t)(k >> 8) * 256 + (k & 255)) * 256 + col]
                            : root2[(size_t)(k - 768) * 256 + col];
        Wf[idx] = f2b(v);
    }
}

// ---------------- prep2: count_edges + L2-resident table build
// tb2 rows [0,256): tabSC[r][s*8+c] = tab[r][s]+tab[r][8+c] (+b1 for r=3)
// tb2 rows [256,768): tabP[r][p]    = tab[r][16+p]
__global__ __launch_bounds__(256) void prep2(const int* __restrict__ ei,
                                             const int* __restrict__ et,
                                             int* __restrict__ cnt,
                                             const float* __restrict__ tab,
                                             const float* __restrict__ b1,
                                             bf16* __restrict__ tb2) {
    int b = blockIdx.x, t = threadIdx.x;
    if (b < P2_CNT) {
        int e = b * 256 + t;
        if (e < NE) atomicAdd(&cnt[ei[NE + e] * NR + et[e]], 1);
        return;
    }
    b -= P2_CNT;
    if (b < 256) {          // SC rows
        int r = b >> 6, sc = b & 63, si = sc >> 3, ci = sc & 7;
        float v = tab[((size_t)r * 144 + si) * 256 + t]
                + tab[((size_t)r * 144 + 8 + ci) * 256 + t];
        if (r == 3) v += b1[t];
        tb2[(size_t)b * 256 + t] = f2b(v);
    } else {                // P rows
        int bb = b - 256;
        int r = bb >> 7, pi = bb & 127;
        tb2[(size_t)(256 + bb) * 256 + t] =
            f2b(tab[((size_t)r * 144 + 16 + pi) * 256 + t]);
    }
}

// ---------------- prep3: tbf = fragment-ordered copy of tb2 (768 K x 256 cols)
__global__ __launch_bounds__(256) void prep3(const bf16* __restrict__ tb2,
                                             bf16* __restrict__ tbf) {
    int idx = blockIdx.x * 256 + threadIdx.x;       // < 768*256 = 196608
    int j = idx & 7, lane = (idx >> 3) & 63, ni = (idx >> 9) & 3;
    int rest = idx >> 11;                           // colblk*24 + chunk, < 96
    int chunk = rest % 24, colblk = rest / 24;
    int col = colblk * 64 + ni * 16 + (lane & 15);
    int k   = chunk * 32 + (lane >> 4) * 8 + j;
    tbf[idx] = tb2[(size_t)k * 256 + col];
}

// ---------------- counting-sort scan, phase A: per-block (2048-elem) totals
__global__ __launch_bounds__(256) void scan_block_sums(const int* __restrict__ cnt,
                                                       int* __restrict__ bsum) {
    __shared__ int sm[256];
    int b = blockIdx.x, t = threadIdx.x;
    int base = b * CHUNK + t * 8, s = 0;
#pragma unroll
    for (int j = 0; j < 8; ++j) { int i = base + j; if (i < NB) s += cnt[i]; }
    sm[t] = s; __syncthreads();
    for (int st = 128; st; st >>= 1) { if (t < st) sm[t] += sm[t + st]; __syncthreads(); }
    if (!t) bsum[b] = sm[0];
}

// ---------------- phase B+C merged: 74-elem wave-uniform prefix over bsum + in-block scan
__global__ __launch_bounds__(256) void scan_write(const int* __restrict__ cnt,
                                                  const int* __restrict__ bsum,
                                                  int* __restrict__ off,
                                                  int* __restrict__ cursor) {
    int b = blockIdx.x, t = threadIdx.x;
    int bbase = 0;                              // wave-uniform 74-iteration prefix
    for (int i = 0; i < b; ++i) bbase += bsum[i];
    if (b == 0 && t == 0) {
        int tot = 0;
        for (int i = 0; i < NBLK; ++i) tot += bsum[i];
        off[NB] = tot;                          // == NE
    }
    int base = b * CHUNK + t * 8;
    int v[8], ts = 0;
#pragma unroll
    for (int j = 0; j < 8; ++j) { int i = base + j; v[j] = (i < NB) ? cnt[i] : 0; ts += v[j]; }
    int lane = t & 63, wv = t >> 6;
    int incl = ts;
    for (int d = 1; d < 64; d <<= 1) {
        int o = __shfl_up(incl, d, 64);
        if (lane >= d) incl += o;
    }
    __shared__ int wsum[4];
    if (lane == 63) wsum[wv] = incl;
    __syncthreads();
    int wbase = 0;
    for (int w = 0; w < wv; ++w) wbase += wsum[w];
    int run = bbase + wbase + incl - ts;
#pragma unroll
    for (int j = 0; j < 8; ++j) {
        int i = base + j;
        if (i < NB) { off[i] = run; cursor[i] = run; }
        run += v[j];
    }
}

// ---------------- bucket-sort edges: single packed-4B scatter
// esc entry = (src << 13) | combo[src]   (src < 2^16, combo < 2^13)
__global__ __launch_bounds__(256) void scatter_edges(const int* __restrict__ ei,
                                                     const int* __restrict__ et,
                                                     const int* __restrict__ combo,
                                                     int* __restrict__ cursor,
                                                     unsigned* __restrict__ esc) {
    int e = blockIdx.x * 256 + threadIdx.x;
    if (e >= NE) return;
    int b = ei[NE + e] * NR + et[e];
    int pos = atomicAdd(&cursor[b], 1);
    int s = ei[e];
    esc[pos] = ((unsigned)s << 13) | (unsigned)combo[s];
}

// ---------------- layer 1 as histogram-GEMM (validated r11: VALU gather -> MFMA)
__global__ __launch_bounds__(256) void l1_hist(const int* __restrict__ off,
                                               const unsigned* __restrict__ esc,
                                               const int* __restrict__ combo,
                                               const bf16* __restrict__ tbf,
                                               bf16* __restrict__ h1) {
    __shared__ __align__(16) unsigned char HIST[L1_DPB * L1_HS];   // 49664 B
    __shared__ int SOFF[193];
    __shared__ float INV[L1_DPB][4];
    const int t = threadIdx.x;
    const int dst0 = blockIdx.x * L1_DPB;

    // ---- phase 1: zero hist + load (clamped) bucket offsets
    for (int i = t; i < (L1_DPB * L1_HS) / 4; i += 256)
        ((unsigned*)HIST)[i] = 0u;
    for (int i = t; i < 193; i += 256)
        SOFF[i] = off[min(dst0 * NR + i, NB)];
    __syncthreads();

    // ---- phase 2: inv table, root one-hots, edge histogram
    if (t < L1_DPB) {
        int base = 3 * t;
#pragma unroll
        for (int r = 0; r < 3; ++r) {
            int c = SOFF[base + r + 1] - SOFF[base + r];
            INV[t][r] = (c > 0) ? 1.f / (float)c : 0.f;
        }
        INV[t][3] = 1.f;
        if (dst0 + t < NN) {                    // root one-hots (rel-3 rows: no
            int c = combo[dst0 + t];            //  overlap with edge rows)
            HIST[t * L1_HS + 192 + (c >> 7)] = 1;
            HIST[t * L1_HS + 640 + (c & 127)] = 1;
        }
    }
    int E0 = SOFF[0], E1 = SOFF[192];
    for (int e = E0 + t; e < E1; e += 256) {    // coalesced esc stream
        unsigned ev = esc[e];
        int lo = 0, hi = 191;                   // largest i with SOFF[i] <= e
#pragma unroll 1
        while (lo < hi) {
            int mid = (lo + hi + 1) >> 1;
            if (SOFF[mid] <= e) lo = mid; else hi = mid - 1;
        }
        int dr = lo / 3, rel = lo - dr * 3;
        int sc = (int)((ev & 8191u) >> 7), p = (int)(ev & 127u);
        int a1 = dr * L1_HS + rel * 64 + sc;            // SC row
        int a2 = dr * L1_HS + 256 + rel * 128 + p;      // P row
        atomicAdd((unsigned*)&HIST[a1 & ~3], 1u << (8 * (a1 & 3)));
        atomicAdd((unsigned*)&HIST[a2 & ~3], 1u << (8 * (a2 & 3)));
    }
    __syncthreads();

    // ---- phase 3: GEMM 64x768 @ 768x256, A from LDS hist, B frags from tbf
    const int wave = t >> 6, lane = t & 63;
    const int quad = lane >> 4, l16 = lane & 15;
    const short8* bb = (const short8*)tbf + (size_t)wave * 24 * 4 * 64 + lane;
    floatx4 acc[4][4] = {};
#pragma unroll 4
    for (int ch = 0; ch < 24; ++ch) {
        short8 bf_[4];
        const short8* bp = bb + (size_t)ch * 4 * 64;
#pragma unroll
        for (int ni = 0; ni < 4; ++ni) bf_[ni] = bp[ni * 64];
        int kb = ch * 32 + quad * 8;
        int iv = (kb < 256) ? (kb >> 6) : ((kb - 256) >> 7);
#pragma unroll
        for (int mi = 0; mi < 4; ++mi) {
            int row = mi * 16 + l16;
            unsigned hx = *(const unsigned*)&HIST[row * L1_HS + kb];
            unsigned hy = *(const unsigned*)&HIST[row * L1_HS + kb + 4];
            float w = INV[row][iv];
            short8 af;
            af[0] = f2bs((float)(hx & 0xffu) * w);
            af[1] = f2bs((float)((hx >> 8) & 0xffu) * w);
            af[2] = f2bs((float)((hx >> 16) & 0xffu) * w);
            af[3] = f2bs((float)(hx >> 24) * w);
            af[4] = f2bs((float)(hy & 0xffu) * w);
            af[5] = f2bs((float)((hy >> 8) & 0xffu) * w);
            af[6] = f2bs((float)((hy >> 16) & 0xffu) * w);
            af[7] = f2bs((float)(hy >> 24) * w);
#pragma unroll
            for (int ni = 0; ni < 4; ++ni)
                acc[mi][ni] = __builtin_amdgcn_mfma_f32_16x16x32_bf16(af, bf_[ni], acc[mi][ni], 0, 0, 0);
        }
    }

    // ---- phase 4: relu + stage (reuse hist LDS, stride 264 shorts) + write
    __syncthreads();
    short* st = (short*)HIST;                   // 64*264*2 = 33792 B <= 49664
    // C/D layout: col = lane&15, row = quad*4 + reg   [m89/m91-verified]
#pragma unroll
    for (int mi = 0; mi < 4; ++mi)
#pragma unroll
        for (int ni = 0; ni < 4; ++ni)
#pragma unroll
            for (int ii = 0; ii < 4; ++ii) {
                int row = mi * 16 + quad * 4 + ii;
                int col = wave * 64 + ni * 16 + l16;
                st[row * 264 + col] = f2bs(fmaxf(acc[mi][ni][ii], 0.f));
            }
    __syncthreads();
    int row = t >> 2, cb = (t & 3) * 64;
    if (dst0 + row < NN) {
#pragma unroll
        for (int j = 0; j < 8; ++j)
            *(short8*)(h1 + (size_t)(dst0 + row) * 256 + cb + j * 8) =
                *(const short8*)&st[row * 264 + cb + j * 8];
    }
}

// ---------------- per-relation mean aggregation v4 (validated r12): maskless
// common prefix + short masked tails; 6 exact rows in flight; scalar CSR/esc.
__global__ __launch_bounds__(256, 4) void agg_all(const int* __restrict__ off,
                                                  const unsigned* __restrict__ esc,
                                                  const bf16* __restrict__ h1,
                                                  bf16* __restrict__ hagg) {
    int wave = threadIdx.x >> 6, lane = threadIdx.x & 63;
    int dst = blockIdx.x * 4 + wave;
    if (dst >= NN) return;
    int l4 = lane * 4;
    int b0 = dst * NR;
    int o0 = rfl(off[b0]),     o1 = rfl(off[b0 + 1]),
        o2 = rfl(off[b0 + 2]), o3 = rfl(off[b0 + 3]);
    int nmin = min(o1 - o0, min(o2 - o1, o3 - o2));
    float s0[4] = {}, s1[4] = {}, s2[4] = {};
    int k = 0;
    for (; k + 2 <= nmin; k += 2) {             // 6 exact rows in flight, maskless
        unsigned ea0 = esc[o0 + k], ea1 = esc[o0 + k + 1];
        unsigned eb0 = esc[o1 + k], eb1 = esc[o1 + k + 1];
        unsigned ec0 = esc[o2 + k], ec1 = esc[o2 + k + 1];
        shortx4 va0 = *(const shortx4*)(h1 + (size_t)(ea0 >> 13) * 256 + l4);
        shortx4 va1 = *(const shortx4*)(h1 + (size_t)(ea1 >> 13) * 256 + l4);
        shortx4 vb0 = *(const shortx4*)(h1 + (size_t)(eb0 >> 13) * 256 + l4);
        shortx4 vb1 = *(const shortx4*)(h1 + (size_t)(eb1 >> 13) * 256 + l4);
        shortx4 vc0 = *(const shortx4*)(h1 + (size_t)(ec0 >> 13) * 256 + l4);
        shortx4 vc1 = *(const shortx4*)(h1 + (size_t)(ec1 >> 13) * 256 + l4);
#pragma unroll
        for (int i = 0; i < 4; ++i) {
            s0[i] += bs2f(va0[i]) + bs2f(va1[i]);
            s1[i] += bs2f(vb0[i]) + bs2f(vb1[i]);
            s2[i] += bs2f(vc0[i]) + bs2f(vc1[i]);
        }
    }
    // per-relation tails, 2-deep, <=1 duplicate load when tail length odd
    for (int j = o0 + k; j < o1; j += 2) {
        bool g = j + 1 < o1;
        unsigned e0 = esc[j], e1 = esc[g ? j + 1 : j];
        shortx4 v0 = *(const shortx4*)(h1 + (size_t)(e0 >> 13) * 256 + l4);
        shortx4 v1 = *(const shortx4*)(h1 + (size_t)(e1 >> 13) * 256 + l4);
        float m = g ? 1.f : 0.f;
#pragma unroll
        for (int i = 0; i < 4; ++i) s0[i] += bs2f(v0[i]) + bs2f(v1[i]) * m;
    }
    for (int j = o1 + k; j < o2; j += 2) {
        bool g = j + 1 < o2;
        unsigned e0 = esc[j], e1 = esc[g ? j + 1 : j];
        shortx4 v0 = *(const shortx4*)(h1 + (size_t)(e0 >> 13) * 256 + l4);
        shortx4 v1 = *(const shortx4*)(h1 + (size_t)(e1 >> 13) * 256 + l4);
        float m = g ? 1.f : 0.f;
#pragma unroll
        for (int i = 0; i < 4; ++i) s1[i] += bs2f(v0[i]) + bs2f(v1[i]) * m;
    }
    for (int j = o2 + k; j < o3; j += 2) {
        bool g = j + 1 < o3;
        unsigned e0 = esc[j], e1 = esc[g ? j + 1 : j];
        shortx4 v0 = *(const shortx4*)(h1 + (size_t)(e0 >> 13) * 256 + l4);
        shortx4 v1 = *(const shortx4*)(h1 + (size_t)(e1 >> 13) * 256 + l4);
        float m = g ? 1.f : 0.f;
#pragma unroll
        for (int i = 0; i < 4; ++i) s2[i] += bs2f(v0[i]) + bs2f(v1[i]) * m;
    }
    float inv0 = (o1 > o0) ? 1.f / (float)(o1 - o0) : 0.f;
    float inv1 = (o2 > o1) ? 1.f / (float)(o2 - o1) : 0.f;
    float inv2 = (o3 > o2) ? 1.f / (float)(o3 - o2) : 0.f;
    shortx4 w0, w1, w2;
#pragma unroll
    for (int i = 0; i < 4; ++i) {
        w0[i] = f2bs(s0[i] * inv0);
        w1[i] = f2bs(s1[i] * inv1);
        w2[i] = f2bs(s2[i] * inv2);
    }
    bf16* hd = hagg + (size_t)dst * 768 + l4;
    *(shortx4*)(hd)       = w0;
    *(shortx4*)(hd + 256) = w1;
    *(shortx4*)(hd + 512) = w2;
}

// ---------------- concat MFMA GEMM v11: v8 geometry (32 rows, LDS-staged —
// empirically best) with a 4-DEEP register pipeline. Loads for chunk i+4..i+7
// are issued while computing i..i+3, giving ~4 chunks (~500-600 cy) of load
// lead vs ~1 chunk before. Four named buffer sets + four per-wave LDS parity
// buffers (all compile-time indexed). + fused bias/relu + fused RLE pooling.
__global__ __launch_bounds__(256) void gemm_cat(const bf16* __restrict__ hagg,
                                                const bf16* __restrict__ h1,
                                                const bf16* __restrict__ Wf,
                                                const float* __restrict__ bias,
                                                const int* __restrict__ batch,
                                                float* __restrict__ pool,
                                                float* __restrict__ gcnt) {
    __shared__ short lds[4][4][32 * 40];    // 40960 B: per-wave 4-parity A buf
    const int t = threadIdx.x;
    const int wave = t >> 6, lane = t & 63;
    const int quad = lane >> 4, l16 = lane & 15;
    const int row0 = blockIdx.x * 32;
    const int colblk = wave;                // 0..3 -> 64-col group
    const int rsub = lane >> 2;        // 0..15: row within 16-row half
    const int ksub = (lane & 3) * 8;   // k-element offset within 32-chunk

    const int r0 = min(row0 + rsub, NN - 1);        // clamped (uses guarded)
    const int r1 = min(row0 + 16 + rsub, NN - 1);
    const bf16* gA0 = hagg + (size_t)r0 * 768 + ksub;
    const bf16* gA1 = hagg + (size_t)r1 * 768 + ksub;
    const bf16* gH0 = h1 + (size_t)r0 * 256 + ksub;
    const bf16* gH1 = h1 + (size_t)r1 * 256 + ksub;
    const short8* bbase = (const short8*)Wf + (size_t)colblk * 32 * 4 * 64 + lane;

    auto loadA2 = [&](int k0, short8& a0, short8& a1) {
        if (k0 < 768) { a0 = *(const short8*)(gA0 + k0); a1 = *(const short8*)(gA1 + k0); }
        else          { a0 = *(const short8*)(gH0 + k0 - 768); a1 = *(const short8*)(gH1 + k0 - 768); }
    };
    auto loadB = [&](int chunk, short8* bf4) {
        const short8* bp = bbase + (size_t)chunk * 4 * 64;
#pragma unroll
        for (int ni = 0; ni < 4; ++ni) bf4[ni] = bp[ni * 64];
    };

    floatx4 acc[2][4] = {};
    short8 a0_[4], a1_[4], b_[4][4];        // 4 named buffer sets (q compile-time)
#pragma unroll
    for (int q = 0; q < 4; ++q) { loadA2(q * 32, a0_[q], a1_[q]); loadB(q, b_[q]); }

#pragma unroll
    for (int i = 0; i < 32; i += 4) {
#pragma unroll
        for (int q = 0; q < 4; ++q) {
            int ch = i + q;
            // stage chunk ch (loaded 4 chunks ago) into parity buffer q
            *(short8*)&lds[wave][q][rsub * 40 + ksub] = a0_[q];
            *(short8*)&lds[wave][q][(16 + rsub) * 40 + ksub] = a1_[q];
            short8 af0 = *(const short8*)&lds[wave][q][l16 * 40 + quad * 8];
            short8 af1 = *(const short8*)&lds[wave][q][(16 + l16) * 40 + quad * 8];
#pragma unroll
            for (int ni = 0; ni < 4; ++ni) {
                acc[0][ni] = __builtin_amdgcn_mfma_f32_16x16x32_bf16(af0, b_[q][ni], acc[0][ni], 0, 0, 0);
                acc[1][ni] = __builtin_amdgcn_mfma_f32_16x16x32_bf16(af1, b_[q][ni], acc[1][ni], 0, 0, 0);
            }
            if (ch + 4 < 32) { loadA2((ch + 4) * 32, a0_[q], a1_[q]); loadB(ch + 4, b_[q]); }
        }
    }

    // ---- epilogue: stage bf16 h2 tile into reused LDS (stride 264), then RLE pooling
    __syncthreads();                        // all waves done with A-LDS
    short* st = &lds[0][0][0];              // 32*264 = 8448 shorts <= 20480 avail
    // C/D layout: col = lane&15, row = quad*4 + reg   [m89/m91-verified]
#pragma unroll
    for (int mi = 0; mi < 2; ++mi) {
#pragma unroll
        for (int ni = 0; ni < 4; ++ni) {
            int n = colblk * 64 + ni * 16 + l16;
            float bn = bias[n];
#pragma unroll
            for (int ii = 0; ii < 4; ++ii) {
                int lrow = mi * 16 + quad * 4 + ii;
                float v = (row0 + lrow < NN) ? fmaxf(acc[mi][ni][ii] + bn, 0.f) : 0.f;
                st[lrow * 264 + n] = f2bs(v);
            }
        }
    }
    __syncthreads();
    int nrows = NN - row0; if (nrows > 32) nrows = 32;
    int curg = batch[row0];                 // wave-uniform broadcast
    float a = 0.f, cntf = 0.f;
    for (int rr = 0; rr < nrows; ++rr) {
        int g = batch[row0 + rr];
        if (g != curg) {
            atomicAdd(&pool[(size_t)curg * 256 + t], a);
            if (t == 0) atomicAdd(&gcnt[curg], cntf);
            a = 0.f; cntf = 0.f; curg = g;
        }
        a += bs2f(st[rr * 264 + t]);
        cntf += 1.f;
    }
    atomicAdd(&pool[(size_t)curg * 256 + t], a);
    if (t == 0) atomicAdd(&gcnt[curg], cntf);
}

// ---------------- head: out[g][c] = (pool[g]/cnt[g]) @ lin_w + lin_b  (f32 out)
__global__ __launch_bounds__(256) void final_head(const float* __restrict__ pool,
                                                  const float* __restrict__ gcnt,
                                                  const float* __restrict__ lin_w,
                                                  const float* __restrict__ lin_b,
                                                  float* __restrict__ out) {
    __shared__ float sm[256];
    int g = blockIdx.x, t = threadIdx.x;
    float inv = 1.0f / fmaxf(gcnt[g], 1.0f);
    sm[t] = pool[(size_t)g * 256 + t] * inv;
    __syncthreads();
    if (t < NCLS) {
        float s = lin_b[t];
        for (int d = 0; d < 256; ++d) s += sm[d] * lin_w[d * NCLS + t];
        out[g * NCLS + t] = s;
    }
}

extern "C" void kernel_launch(void* const* d_in, const int* in_sizes, int n_in,
                              void* d_out, int out_size, void* d_ws, size_t ws_size,
                              hipStream_t stream) {
    const int*   s_idx = (const int*)d_in[0];
    const int*   c_idx = (const int*)d_in[1];
    const int*   p_idx = (const int*)d_in[2];
    const int*   ei    = (const int*)d_in[3];   // (2, NE)
    const int*   et    = (const int*)d_in[4];
    const int*   batch = (const int*)d_in[5];
    const float* se    = (const float*)d_in[6];
    const float* ce    = (const float*)d_in[7];
    const float* pe    = (const float*)d_in[8];
    const float* W1    = (const float*)d_in[9];   // (3, 384, 256)
    const float* root1 = (const float*)d_in[10];  // (384, 256)
    const float* b1    = (const float*)d_in[11];
    const float* W2    = (const float*)d_in[12];  // (3, 256, 256)
    const float* root2 = (const float*)d_in[13];  // (256, 256)
    const float* b2    = (const float*)d_in[14];
    const float* lin_w = (const float*)d_in[15];
    const float* lin_b = (const float*)d_in[16];
    float* out = (float*)d_out;

    // ---- workspace carve-up (~129 MB)
    char* w = (char*)d_ws;
    size_t o = 0;
    auto alloc = [&](size_t bytes) -> void* {
        o = (o + 15) & ~(size_t)15;
        void* ptr = w + o;
        o += bytes;
        return ptr;
    };
    bf16*     hagg   = (bf16*)    alloc((size_t)NN * 768 * 2);   // 76.8 MB
    bf16*     h1     = (bf16*)    alloc((size_t)NN * 256 * 2);
    bf16*     tb2    = (bf16*)    alloc((size_t)768 * 256 * 2);  // 393 KB L2-resident tables
    bf16*     tbf    = (bf16*)    alloc((size_t)768 * 256 * 2);  // fragment-ordered tb2
    int*      combo  = (int*)     alloc((size_t)NN * 4);
    unsigned* esc    = (unsigned*)alloc((size_t)NE * 4);   // (src<<13)|combo
    int*      cnt    = (int*)     alloc((size_t)NB * 4);
    int*      off    = (int*)     alloc((size_t)(NB + 1) * 4);
    int*      cursor = (int*)     alloc((size_t)NB * 4);
    int*      bsum   = (int*)     alloc((size_t)NBLK * 4);
    float*    tab    = (float*)   alloc((size_t)4 * 144 * 256 * 4);
    bf16*     Wf     = (bf16*)    alloc((size_t)256 * 1024 * 2);
    float*    pool   = (float*)   alloc((size_t)NG * 256 * 4);  // pool + gcnt contiguous
    float*    gcnt   = (float*)   alloc((size_t)NG * 4);
    (void)ws_size;

    // ---- 1. all independent prep (combo ids, zeros, layer-1 tab GEMM, Wf shuffle)
    prep1<<<P1_TOTAL, 256, 0, stream>>>(s_idx, c_idx, p_idx, se, ce, pe,
                                        W1, root1, W2, root2,
                                        combo, (unsigned*)cnt, (unsigned*)pool, tab, Wf);
    // ---- 2. edge counts + SC/P table build
    prep2<<<P2_TOTAL, 256, 0, stream>>>(ei, et, cnt, tab, b1, tb2);
    // ---- 2b. fragment-ordered tb2 for the l1 GEMM
    prep3<<<768, 256, 0, stream>>>(tb2, tbf);
    // ---- 3-4. CSR scan (two-kernel form: parallel block sums + cheap bsum prefix)
    scan_block_sums<<<NBLK, 256, 0, stream>>>(cnt, bsum);
    scan_write<<<NBLK, 256, 0, stream>>>(cnt, bsum, off, cursor);
    // ---- 5. bucket-sort edges (packed 4B scatter)
    scatter_edges<<<(NE + 255) / 256, 256, 0, stream>>>(ei, et, combo, cursor, esc);
    // ---- 6. layer 1 as histogram-GEMM (VALU gather -> MFMA)
    l1_hist<<<L1_BLOCKS, 256, 0, stream>>>(off, esc, combo, tbf, h1);
    // ---- 7. layer 2 aggregation (v4: maskless prefix + short tails)
    agg_all<<<(NN + 3) / 4, 256, 0, stream>>>(off, esc, h1, hagg);
    // ---- 8. concat GEMM v11 (4-deep pipelined, LDS-staged) + bias/relu + pooling
    gemm_cat<<<(NN + 31) / 32, 256, 0, stream>>>(hagg, h1, Wf, b2, batch, pool, gcnt);
    // ---- 9. head
    final_head<<<NG, 256, 0, stream>>>(pool, gcnt, lin_w, lin_b, out);
}

// Round 17
// 357.340 us; speedup vs baseline: 1.0876x; 1.0093x over previous
//
#include <hip/hip_runtime.h>
#include <hip/hip_bf16.h>

#define NN 50000          // nodes
#define NE 800000         // edges
#define NR 3              // relations
#define NG 500            // graphs
#define NB (NN * NR)      // (dst, rel) buckets = 150000
#define NCLS 10
#define NCMB 8192         // 8 shapes * 8 colors * 128 positions
#define CHUNK 2048        // scan elements per block
#define NBLK ((NB + CHUNK - 1) / CHUNK)   // 74

// prep1 role block ranges (zeroing moved to hipMemsetAsync; count merged in)
#define P1_COMBO   196                        // node_combo: 50000/256
#define P1_TAB     576                        // tab_gemm: 4*144
#define P1_WF      1024                       // conv_w2cat: 256*1024/256
#define P1_CNT     3125                       // count_edges: NE/256
#define P1_TOTAL   (P1_COMBO + P1_TAB + P1_WF + P1_CNT)   // 4921

// l1_hist geometry
#define L1_DPB     64                         // dsts per block
#define L1_HS      776                        // hist row stride (bytes; breaks 768 bank pattern)
#define L1_BLOCKS  ((NN + L1_DPB - 1) / L1_DPB)   // 782

typedef __hip_bfloat16 bf16;
typedef __attribute__((ext_vector_type(8))) short short8;   // bf16x8 MFMA frag
typedef __attribute__((ext_vector_type(4))) short shortx4;  // bf16x4 gather unit
typedef __attribute__((ext_vector_type(4))) float floatx4;  // MFMA accumulator

static __device__ __forceinline__ float b2f(bf16 x) { return __bfloat162float(x); }
static __device__ __forceinline__ bf16  f2b(float x) { return __float2bfloat16(x); }
static __device__ __forceinline__ float bs2f(short x) {
    return __bfloat162float(*reinterpret_cast<const bf16*>(&x));
}
static __device__ __forceinline__ short f2bs(float x) {
    bf16 b = __float2bfloat16(x);
    return *reinterpret_cast<const short*>(&b);
}
static __device__ __forceinline__ int rfl(int x) {
    return __builtin_amdgcn_readfirstlane(x);
}

// ---------------- prep1: combo ids + tab GEMM + Wf shuffle + edge counting
// (cnt zeroed by hipMemsetAsync before this kernel; count atomics overlap
// with the tab/Wf compute blocks instead of running serially exposed)
__global__ __launch_bounds__(256) void prep1(const int* __restrict__ s,
                                             const int* __restrict__ c,
                                             const int* __restrict__ p,
                                             const float* __restrict__ se,
                                             const float* __restrict__ ce,
                                             const float* __restrict__ pe,
                                             const float* __restrict__ W1,
                                             const float* __restrict__ root1,
                                             const float* __restrict__ W2,
                                             const float* __restrict__ root2,
                                             const int* __restrict__ ei,
                                             const int* __restrict__ et,
                                             int* __restrict__ combo,
                                             int* __restrict__ cnt,
                                             float* __restrict__ tab,
                                             bf16* __restrict__ Wf) {
    int b = blockIdx.x, t = threadIdx.x;
    if (b < P1_COMBO) {
        int n = b * 256 + t;
        if (n < NN) combo[n] = (s[n] << 10) | (c[n] << 7) | p[n];
        return;
    }
    b -= P1_COMBO;
    if (b < P1_TAB) {
        // tab[r][row][n]: rows 0..7 = se@Wseg0, 8..15 = ce@Wseg1, 16..143 = pe@Wseg2
        int r = b / 144, row = b % 144;
        const float* A; int segk;
        if (row < 8)       { A = se + row * 128;        segk = 0; }
        else if (row < 16) { A = ce + (row - 8) * 128;  segk = 128; }
        else               { A = pe + (row - 16) * 128; segk = 256; }
        const float* W = (r < 3) ? (W1 + (size_t)r * 384 * 256) : root1;
        float acc = 0.f;
        for (int k = 0; k < 128; ++k)
            acc += A[k] * W[(size_t)(segk + k) * 256 + t];
        tab[((size_t)r * 144 + row) * 256 + t] = acc;
        return;
    }
    b -= P1_TAB;
    if (b < P1_WF) {    // conv_w2cat: Wf in MFMA-fragment order
        int idx = b * 256 + t;
        int j     = idx & 7;
        int lane  = (idx >> 3) & 63;
        int ni    = (idx >> 9) & 3;
        int chunk = (idx >> 11) & 31;
        int colblk = idx >> 16;
        int col = colblk * 64 + ni * 16 + (lane & 15);
        int k   = chunk * 32 + (lane >> 4) * 8 + j;
        float v = (k < 768) ? W2[((size_t)(k >> 8) * 256 + (k & 255)) * 256 + col]
                            : root2[(size_t)(k - 768) * 256 + col];
        Wf[idx] = f2b(v);
        return;
    }
    b -= P1_WF;
    {   // count_edges
        int e = b * 256 + t;
        if (e < NE) atomicAdd(&cnt[ei[NE + e] * NR + et[e]], 1);
    }
}

// ---------------- prep2: tbf built DIRECTLY from tab (tb2 eliminated).
// tbf fragment element idx -> (k,col); value = tb2-formula at (k,col):
// k<256: SC row (tab[r][s]+tab[r][8+c], +b1 for r=3); else P row tab[r][16+p].
__global__ __launch_bounds__(256) void prep2(const float* __restrict__ tab,
                                             const float* __restrict__ b1,
                                             bf16* __restrict__ tbf) {
    int idx = blockIdx.x * 256 + threadIdx.x;       // < 768*256 = 196608
    int j = idx & 7, lane = (idx >> 3) & 63, ni = (idx >> 9) & 3;
    int rest = idx >> 11;                           // colblk*24 + chunk, < 96
    int chunk = rest % 24, colblk = rest / 24;
    int col = colblk * 64 + ni * 16 + (lane & 15);
    int k   = chunk * 32 + (lane >> 4) * 8 + j;     // tb2-row index [0,768)
    float v;
    if (k < 256) {
        int r = k >> 6, sc = k & 63;
        v = tab[((size_t)r * 144 + (sc >> 3)) * 256 + col]
          + tab[((size_t)r * 144 + 8 + (sc & 7)) * 256 + col];
        if (r == 3) v += b1[col];
    } else {
        int kk = k - 256, r = kk >> 7, pi = kk & 127;
        v = tab[((size_t)r * 144 + 16 + pi) * 256 + col];
    }
    tbf[idx] = f2b(v);
}

// ---------------- counting-sort scan, phase A: per-block (2048-elem) totals
__global__ __launch_bounds__(256) void scan_block_sums(const int* __restrict__ cnt,
                                                       int* __restrict__ bsum) {
    __shared__ int sm[256];
    int b = blockIdx.x, t = threadIdx.x;
    int base = b * CHUNK + t * 8, s = 0;
#pragma unroll
    for (int j = 0; j < 8; ++j) { int i = base + j; if (i < NB) s += cnt[i]; }
    sm[t] = s; __syncthreads();
    for (int st = 128; st; st >>= 1) { if (t < st) sm[t] += sm[t + st]; __syncthreads(); }
    if (!t) bsum[b] = sm[0];
}

// ---------------- phase B+C merged: 74-elem wave-uniform prefix over bsum + in-block scan
__global__ __launch_bounds__(256) void scan_write(const int* __restrict__ cnt,
                                                  const int* __restrict__ bsum,
                                                  int* __restrict__ off,
                                                  int* __restrict__ cursor) {
    int b = blockIdx.x, t = threadIdx.x;
    int bbase = 0;                              // wave-uniform 74-iteration prefix
    for (int i = 0; i < b; ++i) bbase += bsum[i];
    if (b == 0 && t == 0) {
        int tot = 0;
        for (int i = 0; i < NBLK; ++i) tot += bsum[i];
        off[NB] = tot;                          // == NE
    }
    int base = b * CHUNK + t * 8;
    int v[8], ts = 0;
#pragma unroll
    for (int j = 0; j < 8; ++j) { int i = base + j; v[j] = (i < NB) ? cnt[i] : 0; ts += v[j]; }
    int lane = t & 63, wv = t >> 6;
    int incl = ts;
    for (int d = 1; d < 64; d <<= 1) {
        int o = __shfl_up(incl, d, 64);
        if (lane >= d) incl += o;
    }
    __shared__ int wsum[4];
    if (lane == 63) wsum[wv] = incl;
    __syncthreads();
    int wbase = 0;
    for (int w = 0; w < wv; ++w) wbase += wsum[w];
    int run = bbase + wbase + incl - ts;
#pragma unroll
    for (int j = 0; j < 8; ++j) {
        int i = base + j;
        if (i < NB) { off[i] = run; cursor[i] = run; }
        run += v[j];
    }
}

// ---------------- bucket-sort edges: single packed-4B scatter
// esc entry = (src << 13) | combo[src]   (src < 2^16, combo < 2^13)
__global__ __launch_bounds__(256) void scatter_edges(const int* __restrict__ ei,
                                                     const int* __restrict__ et,
                                                     const int* __restrict__ combo,
                                                     int* __restrict__ cursor,
                                                     unsigned* __restrict__ esc) {
    int e = blockIdx.x * 256 + threadIdx.x;
    if (e >= NE) return;
    int b = ei[NE + e] * NR + et[e];
    int pos = atomicAdd(&cursor[b], 1);
    int s = ei[e];
    esc[pos] = ((unsigned)s << 13) | (unsigned)combo[s];
}

// ---------------- layer 1 as histogram-GEMM (validated r11: VALU gather -> MFMA)
__global__ __launch_bounds__(256) void l1_hist(const int* __restrict__ off,
                                               const unsigned* __restrict__ esc,
                                               const int* __restrict__ combo,
                                               const bf16* __restrict__ tbf,
                                               bf16* __restrict__ h1) {
    __shared__ __align__(16) unsigned char HIST[L1_DPB * L1_HS];   // 49664 B
    __shared__ int SOFF[193];
    __shared__ float INV[L1_DPB][4];
    const int t = threadIdx.x;
    const int dst0 = blockIdx.x * L1_DPB;

    // ---- phase 1: zero hist + load (clamped) bucket offsets
    for (int i = t; i < (L1_DPB * L1_HS) / 4; i += 256)
        ((unsigned*)HIST)[i] = 0u;
    for (int i = t; i < 193; i += 256)
        SOFF[i] = off[min(dst0 * NR + i, NB)];
    __syncthreads();

    // ---- phase 2: inv table, root one-hots, edge histogram
    if (t < L1_DPB) {
        int base = 3 * t;
#pragma unroll
        for (int r = 0; r < 3; ++r) {
            int c = SOFF[base + r + 1] - SOFF[base + r];
            INV[t][r] = (c > 0) ? 1.f / (float)c : 0.f;
        }
        INV[t][3] = 1.f;
        if (dst0 + t < NN) {                    // root one-hots (rel-3 rows: no
            int c = combo[dst0 + t];            //  overlap with edge rows)
            HIST[t * L1_HS + 192 + (c >> 7)] = 1;
            HIST[t * L1_HS + 640 + (c & 127)] = 1;
        }
    }
    int E0 = SOFF[0], E1 = SOFF[192];
    for (int e = E0 + t; e < E1; e += 256) {    // coalesced esc stream
        unsigned ev = esc[e];
        int lo = 0, hi = 191;                   // largest i with SOFF[i] <= e
#pragma unroll 1
        while (lo < hi) {
            int mid = (lo + hi + 1) >> 1;
            if (SOFF[mid] <= e) lo = mid; else hi = mid - 1;
        }
        int dr = lo / 3, rel = lo - dr * 3;
        int sc = (int)((ev & 8191u) >> 7), p = (int)(ev & 127u);
        int a1 = dr * L1_HS + rel * 64 + sc;            // SC row
        int a2 = dr * L1_HS + 256 + rel * 128 + p;      // P row
        atomicAdd((unsigned*)&HIST[a1 & ~3], 1u << (8 * (a1 & 3)));
        atomicAdd((unsigned*)&HIST[a2 & ~3], 1u << (8 * (a2 & 3)));
    }
    __syncthreads();

    // ---- phase 3: GEMM 64x768 @ 768x256, A from LDS hist, B frags from tbf
    const int wave = t >> 6, lane = t & 63;
    const int quad = lane >> 4, l16 = lane & 15;
    const short8* bb = (const short8*)tbf + (size_t)wave * 24 * 4 * 64 + lane;
    floatx4 acc[4][4] = {};
#pragma unroll 4
    for (int ch = 0; ch < 24; ++ch) {
        short8 bf_[4];
        const short8* bp = bb + (size_t)ch * 4 * 64;
#pragma unroll
        for (int ni = 0; ni < 4; ++ni) bf_[ni] = bp[ni * 64];
        int kb = ch * 32 + quad * 8;
        int iv = (kb < 256) ? (kb >> 6) : ((kb - 256) >> 7);
#pragma unroll
        for (int mi = 0; mi < 4; ++mi) {
            int row = mi * 16 + l16;
            unsigned hx = *(const unsigned*)&HIST[row * L1_HS + kb];
            unsigned hy = *(const unsigned*)&HIST[row * L1_HS + kb + 4];
            float w = INV[row][iv];
            short8 af;
            af[0] = f2bs((float)(hx & 0xffu) * w);
            af[1] = f2bs((float)((hx >> 8) & 0xffu) * w);
            af[2] = f2bs((float)((hx >> 16) & 0xffu) * w);
            af[3] = f2bs((float)(hx >> 24) * w);
            af[4] = f2bs((float)(hy & 0xffu) * w);
            af[5] = f2bs((float)((hy >> 8) & 0xffu) * w);
            af[6] = f2bs((float)((hy >> 16) & 0xffu) * w);
            af[7] = f2bs((float)(hy >> 24) * w);
#pragma unroll
            for (int ni = 0; ni < 4; ++ni)
                acc[mi][ni] = __builtin_amdgcn_mfma_f32_16x16x32_bf16(af, bf_[ni], acc[mi][ni], 0, 0, 0);
        }
    }

    // ---- phase 4: relu + stage (reuse hist LDS, stride 264 shorts) + write
    __syncthreads();
    short* st = (short*)HIST;                   // 64*264*2 = 33792 B <= 49664
    // C/D layout: col = lane&15, row = quad*4 + reg   [m89/m91-verified]
#pragma unroll
    for (int mi = 0; mi < 4; ++mi)
#pragma unroll
        for (int ni = 0; ni < 4; ++ni)
#pragma unroll
            for (int ii = 0; ii < 4; ++ii) {
                int row = mi * 16 + quad * 4 + ii;
                int col = wave * 64 + ni * 16 + l16;
                st[row * 264 + col] = f2bs(fmaxf(acc[mi][ni][ii], 0.f));
            }
    __syncthreads();
    int row = t >> 2, cb = (t & 3) * 64;
    if (dst0 + row < NN) {
#pragma unroll
        for (int j = 0; j < 8; ++j)
            *(short8*)(h1 + (size_t)(dst0 + row) * 256 + cb + j * 8) =
                *(const short8*)&st[row * 264 + cb + j * 8];
    }
}

// ---------------- per-relation mean aggregation v4 (validated r12): maskless
// common prefix + short masked tails; 6 exact rows in flight; scalar CSR/esc.
__global__ __launch_bounds__(256, 4) void agg_all(const int* __restrict__ off,
                                                  const unsigned* __restrict__ esc,
                                                  const bf16* __restrict__ h1,
                                                  bf16* __restrict__ hagg) {
    int wave = threadIdx.x >> 6, lane = threadIdx.x & 63;
    int dst = blockIdx.x * 4 + wave;
    if (dst >= NN) return;
    int l4 = lane * 4;
    int b0 = dst * NR;
    int o0 = rfl(off[b0]),     o1 = rfl(off[b0 + 1]),
        o2 = rfl(off[b0 + 2]), o3 = rfl(off[b0 + 3]);
    int nmin = min(o1 - o0, min(o2 - o1, o3 - o2));
    float s0[4] = {}, s1[4] = {}, s2[4] = {};
    int k = 0;
    for (; k + 2 <= nmin; k += 2) {             // 6 exact rows in flight, maskless
        unsigned ea0 = esc[o0 + k], ea1 = esc[o0 + k + 1];
        unsigned eb0 = esc[o1 + k], eb1 = esc[o1 + k + 1];
        unsigned ec0 = esc[o2 + k], ec1 = esc[o2 + k + 1];
        shortx4 va0 = *(const shortx4*)(h1 + (size_t)(ea0 >> 13) * 256 + l4);
        shortx4 va1 = *(const shortx4*)(h1 + (size_t)(ea1 >> 13) * 256 + l4);
        shortx4 vb0 = *(const shortx4*)(h1 + (size_t)(eb0 >> 13) * 256 + l4);
        shortx4 vb1 = *(const shortx4*)(h1 + (size_t)(eb1 >> 13) * 256 + l4);
        shortx4 vc0 = *(const shortx4*)(h1 + (size_t)(ec0 >> 13) * 256 + l4);
        shortx4 vc1 = *(const shortx4*)(h1 + (size_t)(ec1 >> 13) * 256 + l4);
#pragma unroll
        for (int i = 0; i < 4; ++i) {
            s0[i] += bs2f(va0[i]) + bs2f(va1[i]);
            s1[i] += bs2f(vb0[i]) + bs2f(vb1[i]);
            s2[i] += bs2f(vc0[i]) + bs2f(vc1[i]);
        }
    }
    // per-relation tails, 2-deep, <=1 duplicate load when tail length odd
    for (int j = o0 + k; j < o1; j += 2) {
        bool g = j + 1 < o1;
        unsigned e0 = esc[j], e1 = esc[g ? j + 1 : j];
        shortx4 v0 = *(const shortx4*)(h1 + (size_t)(e0 >> 13) * 256 + l4);
        shortx4 v1 = *(const shortx4*)(h1 + (size_t)(e1 >> 13) * 256 + l4);
        float m = g ? 1.f : 0.f;
#pragma unroll
        for (int i = 0; i < 4; ++i) s0[i] += bs2f(v0[i]) + bs2f(v1[i]) * m;
    }
    for (int j = o1 + k; j < o2; j += 2) {
        bool g = j + 1 < o2;
        unsigned e0 = esc[j], e1 = esc[g ? j + 1 : j];
        shortx4 v0 = *(const shortx4*)(h1 + (size_t)(e0 >> 13) * 256 + l4);
        shortx4 v1 = *(const shortx4*)(h1 + (size_t)(e1 >> 13) * 256 + l4);
        float m = g ? 1.f : 0.f;
#pragma unroll
        for (int i = 0; i < 4; ++i) s1[i] += bs2f(v0[i]) + bs2f(v1[i]) * m;
    }
    for (int j = o2 + k; j < o3; j += 2) {
        bool g = j + 1 < o3;
        unsigned e0 = esc[j], e1 = esc[g ? j + 1 : j];
        shortx4 v0 = *(const shortx4*)(h1 + (size_t)(e0 >> 13) * 256 + l4);
        shortx4 v1 = *(const shortx4*)(h1 + (size_t)(e1 >> 13) * 256 + l4);
        float m = g ? 1.f : 0.f;
#pragma unroll
        for (int i = 0; i < 4; ++i) s2[i] += bs2f(v0[i]) + bs2f(v1[i]) * m;
    }
    float inv0 = (o1 > o0) ? 1.f / (float)(o1 - o0) : 0.f;
    float inv1 = (o2 > o1) ? 1.f / (float)(o2 - o1) : 0.f;
    float inv2 = (o3 > o2) ? 1.f / (float)(o3 - o2) : 0.f;
    shortx4 w0, w1, w2;
#pragma unroll
    for (int i = 0; i < 4; ++i) {
        w0[i] = f2bs(s0[i] * inv0);
        w1[i] = f2bs(s1[i] * inv1);
        w2[i] = f2bs(s2[i] * inv2);
    }
    bf16* hd = hagg + (size_t)dst * 768 + l4;
    *(shortx4*)(hd)       = w0;
    *(shortx4*)(hd + 256) = w1;
    *(shortx4*)(hd + 512) = w2;
}

// ---------------- concat MFMA GEMM v11 (r15): 32 rows, LDS-staged, 4-deep
// register pipeline (loads issued 4 chunks ahead). + bias/relu + RLE pooling.
__global__ __launch_bounds__(256) void gemm_cat(const bf16* __restrict__ hagg,
                                                const bf16* __restrict__ h1,
                                                const bf16* __restrict__ Wf,
                                                const float* __restrict__ bias,
                                                const int* __restrict__ batch,
                                                float* __restrict__ pool,
                                                float* __restrict__ gcnt) {
    __shared__ short lds[4][4][32 * 40];    // 40960 B: per-wave 4-parity A buf
    const int t = threadIdx.x;
    const int wave = t >> 6, lane = t & 63;
    const int quad = lane >> 4, l16 = lane & 15;
    const int row0 = blockIdx.x * 32;
    const int colblk = wave;                // 0..3 -> 64-col group
    const int rsub = lane >> 2;        // 0..15: row within 16-row half
    const int ksub = (lane & 3) * 8;   // k-element offset within 32-chunk

    const int r0 = min(row0 + rsub, NN - 1);        // clamped (uses guarded)
    const int r1 = min(row0 + 16 + rsub, NN - 1);
    const bf16* gA0 = hagg + (size_t)r0 * 768 + ksub;
    const bf16* gA1 = hagg + (size_t)r1 * 768 + ksub;
    const bf16* gH0 = h1 + (size_t)r0 * 256 + ksub;
    const bf16* gH1 = h1 + (size_t)r1 * 256 + ksub;
    const short8* bbase = (const short8*)Wf + (size_t)colblk * 32 * 4 * 64 + lane;

    auto loadA2 = [&](int k0, short8& a0, short8& a1) {
        if (k0 < 768) { a0 = *(const short8*)(gA0 + k0); a1 = *(const short8*)(gA1 + k0); }
        else          { a0 = *(const short8*)(gH0 + k0 - 768); a1 = *(const short8*)(gH1 + k0 - 768); }
    };
    auto loadB = [&](int chunk, short8* bf4) {
        const short8* bp = bbase + (size_t)chunk * 4 * 64;
#pragma unroll
        for (int ni = 0; ni < 4; ++ni) bf4[ni] = bp[ni * 64];
    };

    floatx4 acc[2][4] = {};
    short8 a0_[4], a1_[4], b_[4][4];        // 4 named buffer sets (q compile-time)
#pragma unroll
    for (int q = 0; q < 4; ++q) { loadA2(q * 32, a0_[q], a1_[q]); loadB(q, b_[q]); }

#pragma unroll
    for (int i = 0; i < 32; i += 4) {
#pragma unroll
        for (int q = 0; q < 4; ++q) {
            int ch = i + q;
            *(short8*)&lds[wave][q][rsub * 40 + ksub] = a0_[q];
            *(short8*)&lds[wave][q][(16 + rsub) * 40 + ksub] = a1_[q];
            short8 af0 = *(const short8*)&lds[wave][q][l16 * 40 + quad * 8];
            short8 af1 = *(const short8*)&lds[wave][q][(16 + l16) * 40 + quad * 8];
#pragma unroll
            for (int ni = 0; ni < 4; ++ni) {
                acc[0][ni] = __builtin_amdgcn_mfma_f32_16x16x32_bf16(af0, b_[q][ni], acc[0][ni], 0, 0, 0);
                acc[1][ni] = __builtin_amdgcn_mfma_f32_16x16x32_bf16(af1, b_[q][ni], acc[1][ni], 0, 0, 0);
            }
            if (ch + 4 < 32) { loadA2((ch + 4) * 32, a0_[q], a1_[q]); loadB(ch + 4, b_[q]); }
        }
    }

    // ---- epilogue: stage bf16 h2 tile into reused LDS (stride 264), then RLE pooling
    __syncthreads();                        // all waves done with A-LDS
    short* st = &lds[0][0][0];              // 32*264 = 8448 shorts <= 20480 avail
    // C/D layout: col = lane&15, row = quad*4 + reg   [m89/m91-verified]
#pragma unroll
    for (int mi = 0; mi < 2; ++mi) {
#pragma unroll
        for (int ni = 0; ni < 4; ++ni) {
            int n = colblk * 64 + ni * 16 + l16;
            float bn = bias[n];
#pragma unroll
            for (int ii = 0; ii < 4; ++ii) {
                int lrow = mi * 16 + quad * 4 + ii;
                float v = (row0 + lrow < NN) ? fmaxf(acc[mi][ni][ii] + bn, 0.f) : 0.f;
                st[lrow * 264 + n] = f2bs(v);
            }
        }
    }
    __syncthreads();
    int nrows = NN - row0; if (nrows > 32) nrows = 32;
    int curg = batch[row0];                 // wave-uniform broadcast
    float a = 0.f, cntf = 0.f;
    for (int rr = 0; rr < nrows; ++rr) {
        int g = batch[row0 + rr];
        if (g != curg) {
            atomicAdd(&pool[(size_t)curg * 256 + t], a);
            if (t == 0) atomicAdd(&gcnt[curg], cntf);
            a = 0.f; cntf = 0.f; curg = g;
        }
        a += bs2f(st[rr * 264 + t]);
        cntf += 1.f;
    }
    atomicAdd(&pool[(size_t)curg * 256 + t], a);
    if (t == 0) atomicAdd(&gcnt[curg], cntf);
}

// ---------------- head: out[g][c] = (pool[g]/cnt[g]) @ lin_w + lin_b  (f32 out)
__global__ __launch_bounds__(256) void final_head(const float* __restrict__ pool,
                                                  const float* __restrict__ gcnt,
                                                  const float* __restrict__ lin_w,
                                                  const float* __restrict__ lin_b,
                                                  float* __restrict__ out) {
    __shared__ float sm[256];
    int g = blockIdx.x, t = threadIdx.x;
    float inv = 1.0f / fmaxf(gcnt[g], 1.0f);
    sm[t] = pool[(size_t)g * 256 + t] * inv;
    __syncthreads();
    if (t < NCLS) {
        float s = lin_b[t];
        for (int d = 0; d < 256; ++d) s += sm[d] * lin_w[d * NCLS + t];
        out[g * NCLS + t] = s;
    }
}

extern "C" void kernel_launch(void* const* d_in, const int* in_sizes, int n_in,
                              void* d_out, int out_size, void* d_ws, size_t ws_size,
                              hipStream_t stream) {
    const int*   s_idx = (const int*)d_in[0];
    const int*   c_idx = (const int*)d_in[1];
    const int*   p_idx = (const int*)d_in[2];
    const int*   ei    = (const int*)d_in[3];   // (2, NE)
    const int*   et    = (const int*)d_in[4];
    const int*   batch = (const int*)d_in[5];
    const float* se    = (const float*)d_in[6];
    const float* ce    = (const float*)d_in[7];
    const float* pe    = (const float*)d_in[8];
    const float* W1    = (const float*)d_in[9];   // (3, 384, 256)
    const float* root1 = (const float*)d_in[10];  // (384, 256)
    const float* b1    = (const float*)d_in[11];
    const float* W2    = (const float*)d_in[12];  // (3, 256, 256)
    const float* root2 = (const float*)d_in[13];  // (256, 256)
    const float* b2    = (const float*)d_in[14];
    const float* lin_w = (const float*)d_in[15];
    const float* lin_b = (const float*)d_in[16];
    float* out = (float*)d_out;

    // ---- workspace carve-up (~128 MB; tb2 eliminated)
    char* w = (char*)d_ws;
    size_t o = 0;
    auto alloc = [&](size_t bytes) -> void* {
        o = (o + 15) & ~(size_t)15;
        void* ptr = w + o;
        o += bytes;
        return ptr;
    };
    bf16*     hagg   = (bf16*)    alloc((size_t)NN * 768 * 2);   // 76.8 MB
    bf16*     h1     = (bf16*)    alloc((size_t)NN * 256 * 2);
    bf16*     tbf    = (bf16*)    alloc((size_t)768 * 256 * 2);  // fragment-ordered table
    int*      combo  = (int*)     alloc((size_t)NN * 4);
    unsigned* esc    = (unsigned*)alloc((size_t)NE * 4);   // (src<<13)|combo
    int*      cnt    = (int*)     alloc((size_t)NB * 4);
    int*      off    = (int*)     alloc((size_t)(NB + 1) * 4);
    int*      cursor = (int*)     alloc((size_t)NB * 4);
    int*      bsum   = (int*)     alloc((size_t)NBLK * 4);
    float*    tab    = (float*)   alloc((size_t)4 * 144 * 256 * 4);
    bf16*     Wf     = (bf16*)    alloc((size_t)256 * 1024 * 2);
    float*    pool   = (float*)   alloc((size_t)NG * 256 * 4);
    float*    gcnt   = (float*)   alloc((size_t)NG * 4);
    (void)ws_size;

    // ---- 0. async zeroing (graph-capture-safe)
    hipMemsetAsync(cnt, 0, (size_t)NB * 4, stream);
    hipMemsetAsync(pool, 0, (size_t)NG * 256 * 4, stream);
    hipMemsetAsync(gcnt, 0, (size_t)NG * 4, stream);
    // ---- 1. prep (combo ids, tab GEMM, Wf shuffle, edge counting — overlapped)
    prep1<<<P1_TOTAL, 256, 0, stream>>>(s_idx, c_idx, p_idx, se, ce, pe,
                                        W1, root1, W2, root2, ei, et,
                                        combo, cnt, tab, Wf);
    // ---- 2. fragment-ordered table directly from tab (tb2/prep3 eliminated)
    prep2<<<768, 256, 0, stream>>>(tab, b1, tbf);
    // ---- 3-4. CSR scan (two-kernel form: parallel block sums + cheap bsum prefix)
    scan_block_sums<<<NBLK, 256, 0, stream>>>(cnt, bsum);
    scan_write<<<NBLK, 256, 0, stream>>>(cnt, bsum, off, cursor);
    // ---- 5. bucket-sort edges (packed 4B scatter)
    scatter_edges<<<(NE + 255) / 256, 256, 0, stream>>>(ei, et, combo, cursor, esc);
    // ---- 6. layer 1 as histogram-GEMM (VALU gather -> MFMA)
    l1_hist<<<L1_BLOCKS, 256, 0, stream>>>(off, esc, combo, tbf, h1);
    // ---- 7. layer 2 aggregation (v4: maskless prefix + short tails)
    agg_all<<<(NN + 3) / 4, 256, 0, stream>>>(off, esc, h1, hagg);
    // ---- 8. concat GEMM v11 (4-deep pipelined, LDS-staged) + bias/relu + pooling
    gemm_cat<<<(NN + 31) / 32, 256, 0, stream>>>(hagg, h1, Wf, b2, batch, pool, gcnt);
    // ---- 9. head
    final_head<<<NG, 256, 0, stream>>>(pool, gcnt, lin_w, lin_b, out);
}